// Round 1
// 311.988 us; speedup vs baseline: 1.0014x; 1.0014x over previous
//
#include <hip/hip_runtime.h>

// Problem constants (from reference): x:(B,T,2P) f32, resolution:(B,T,2) f32,
// origin:(B,T,2) f32 -> out:(B,T,H,W,P) f32 one-hot raster grid.
#define BB 32
#define TT 10
#define PP 25
#define HH 100
#define WW 100

__global__ void raster_scatter_kernel(const float* __restrict__ x,
                                      const float* __restrict__ resolution,
                                      const float* __restrict__ origin,
                                      float* __restrict__ out) {
    int tid = blockIdx.x * blockDim.x + threadIdx.x;
    const int N = BB * TT * PP;  // 8000
    if (tid >= N) return;

    int p  = tid % PP;
    int bt = tid / PP;           // fused (b,t) index, 0..319

    // points layout: x[bt][2p] = x-coord, x[bt][2p+1] = y-coord
    const float px = x[bt * (2 * PP) + 2 * p];
    const float py = x[bt * (2 * PP) + 2 * p + 1];
    const float r0 = resolution[bt * 2 + 0];  // row uses res[...,0]
    const float r1 = resolution[bt * 2 + 1];  // col uses res[...,1]
    const float o0 = origin[bt * 2 + 0];
    const float o1 = origin[bt * 2 + 1];

    // jnp .astype(int32) truncates toward zero, same as C cast.
    int row = (int)(py / r0 + o0);
    int col = (int)(px / r1 + o1);

    if (row >= 0 && row < HH && col >= 0 && col < WW) {
        size_t idx = (((size_t)bt * HH + (size_t)row) * WW + (size_t)col) * PP + (size_t)p;
        out[idx] = 1.0f;
    }
}

extern "C" void kernel_launch(void* const* d_in, const int* in_sizes, int n_in,
                              void* d_out, int out_size, void* d_ws, size_t ws_size,
                              hipStream_t stream) {
    const float* x          = (const float*)d_in[0];
    const float* resolution = (const float*)d_in[1];
    const float* origin     = (const float*)d_in[2];
    float* out = (float*)d_out;

    // Logical output byte size from problem constants: 32*10*100*100*25 floats
    // = 320,000,000 bytes. rocprof showed the previous out_size*sizeof(float)
    // memset wrote 1.28 GB (WRITE_SIZE counter) => out_size is already a byte
    // count; using the constant is correct under either interpretation and
    // memsets exactly the poisoned output region.
    const size_t out_bytes = (size_t)BB * TT * HH * WW * PP * sizeof(float);
    hipMemsetAsync(out, 0, out_bytes, stream);

    const int N = BB * TT * PP;  // 8000 points
    raster_scatter_kernel<<<(N + 255) / 256, 256, 0, stream>>>(x, resolution, origin, out);
}